// Round 4
// baseline (369.363 us; speedup 1.0000x reference)
//
#include <hip/hip_runtime.h>

#define RR 8
#define TILE 32
#define EXT (TILE + 2 * RR)   // 48

typedef float f4 __attribute__((ext_vector_type(4)));

// Kernel 1: per low-res pixel A = cov/(var+eps), b = mean_y - A*mean_x via
// clamped 17x17 box sums (zero-pad OOB + analytic N). Separable with
// register sliding windows to minimize LDS instruction count.
// Outputs separate A and B planes (k_out stages them as b64 pairs).
__global__ __launch_bounds__(256) void k_ab(
    const float* __restrict__ lrx, const float* __restrict__ lry,
    float* __restrict__ Aout, float* __restrict__ Bout, int H, int W) {
  __shared__ float sx[EXT][EXT];
  __shared__ float sy[EXT][EXT];
  __shared__ float hx[EXT][TILE];
  __shared__ float hy[EXT][TILE];
  __shared__ float hxy[EXT][TILE];
  __shared__ float hxx[EXT][TILE];

  const int bc = blockIdx.z;
  const size_t plane = (size_t)bc * H * W;
  const float* __restrict__ px = lrx + plane;
  const float* __restrict__ py = lry + plane;
  const int tx0 = blockIdx.x * TILE;
  const int ty0 = blockIdx.y * TILE;
  const int tid = threadIdx.y * 32 + threadIdx.x;  // block = 32x8 = 256

  // Stage 48x48 region. Interior blocks (no clamping needed): float4 loads.
  const bool interior = (tx0 >= RR) && (ty0 >= RR) &&
                        (tx0 + TILE + RR <= W) && (ty0 + TILE + RR <= H);
  if (interior) {
    const size_t base = (size_t)(ty0 - RR) * W + (tx0 - RR);
    for (int i = tid; i < EXT * (EXT / 4); i += 256) {  // 48*12 = 576
      int r = i / (EXT / 4);
      int c4 = (i - r * (EXT / 4)) * 4;
      size_t o = base + (size_t)r * W + c4;
      *(float4*)&sx[r][c4] = *(const float4*)(px + o);
      *(float4*)&sy[r][c4] = *(const float4*)(py + o);
    }
  } else {
    for (int i = tid; i < EXT * EXT; i += 256) {
      int r = i / EXT, c = i % EXT;
      int gy = ty0 + r - RR, gx = tx0 + c - RR;
      float vx = 0.f, vy = 0.f;
      if (gy >= 0 && gy < H && gx >= 0 && gx < W) {
        size_t o = (size_t)gy * W + gx;
        vx = px[o];
        vy = py[o];
      }
      sx[r][c] = vx;
      sy[r][c] = vy;
    }
  }
  __syncthreads();

  // Horizontal 17-tap sums: 48 rows x 8 groups of 4 outputs = 384 work items.
  for (int q = tid; q < EXT * (TILE / 4); q += 256) {
    int r = q >> 3;
    int c0 = (q & 7) * 4;
    float xv[20], yv[20];
#pragma unroll
    for (int t = 0; t < 5; ++t) {
      float4 x4 = *(const float4*)&sx[r][c0 + 4 * t];
      float4 y4 = *(const float4*)&sy[r][c0 + 4 * t];
      xv[4 * t + 0] = x4.x; xv[4 * t + 1] = x4.y; xv[4 * t + 2] = x4.z; xv[4 * t + 3] = x4.w;
      yv[4 * t + 0] = y4.x; yv[4 * t + 1] = y4.y; yv[4 * t + 2] = y4.z; yv[4 * t + 3] = y4.w;
    }
    float pv[20], qv[20];
#pragma unroll
    for (int i = 0; i < 20; ++i) { pv[i] = xv[i] * yv[i]; qv[i] = xv[i] * xv[i]; }
    float ax = 0.f, ay = 0.f, axy = 0.f, axx = 0.f;
#pragma unroll
    for (int i = 0; i < 17; ++i) { ax += xv[i]; ay += yv[i]; axy += pv[i]; axx += qv[i]; }
    float4 ox, oy, oxy, oxx;
    ox.x = ax; oy.x = ay; oxy.x = axy; oxx.x = axx;
#pragma unroll
    for (int j = 1; j < 4; ++j) {
      ax += xv[j + 16] - xv[j - 1];
      ay += yv[j + 16] - yv[j - 1];
      axy += pv[j + 16] - pv[j - 1];
      axx += qv[j + 16] - qv[j - 1];
      (&ox.x)[j] = ax; (&oy.x)[j] = ay; (&oxy.x)[j] = axy; (&oxx.x)[j] = axx;
    }
    *(float4*)&hx[r][c0] = ox;
    *(float4*)&hy[r][c0] = oy;
    *(float4*)&hxy[r][c0] = oxy;
    *(float4*)&hxx[r][c0] = oxx;
  }
  __syncthreads();

  // Vertical 17-tap: thread (tx, ty) computes rows ty*4..ty*4+3 at col tx.
  const int c = threadIdx.x;
  const int r0 = threadIdx.y * 4;
  float vx[20], vy[20], vxy[20], vxx[20];
#pragma unroll
  for (int i = 0; i < 20; ++i) {
    vx[i] = hx[r0 + i][c];
    vy[i] = hy[r0 + i][c];
    vxy[i] = hxy[r0 + i][c];
    vxx[i] = hxx[r0 + i][c];
  }
  float sX = 0.f, sY = 0.f, sXY = 0.f, sXX = 0.f;
#pragma unroll
  for (int i = 0; i < 17; ++i) { sX += vx[i]; sY += vy[i]; sXY += vxy[i]; sXX += vxx[i]; }

  const int gx = tx0 + c;
  const int nx = min(gx + RR, W - 1) - max(gx - RR, 0) + 1;
#pragma unroll
  for (int j = 0; j < 4; ++j) {
    if (j > 0) {
      sX += vx[j + 16] - vx[j - 1];
      sY += vy[j + 16] - vy[j - 1];
      sXY += vxy[j + 16] - vxy[j - 1];
      sXX += vxx[j + 16] - vxx[j - 1];
    }
    const int gy = ty0 + r0 + j;
    const int ny = min(gy + RR, H - 1) - max(gy - RR, 0) + 1;
    float inv = 1.f / (float)(nx * ny);
    float mx = sX * inv;
    float my = sY * inv;
    float cov = sXY * inv - mx * my;
    float var = sXX * inv - mx * mx;
    float a = cov / (var + 1e-8f);
    float bv = my - a * mx;
    size_t o = plane + (size_t)gy * W + gx;
    Aout[o] = a;
    Bout[o] = bv;
  }
}

// Kernel 2: bilinear align-corners upsample of A,b fused with out = A*hr+b.
// One block = one FULL HR row (2048 px, 256 threads x 8 px). wy is uniform
// per row, so the y-lerp is done ONCE into LDS (Ay/By, 513 entries, zero
// x-overlap redundancy, amortized over 2048 px). Inner loop per px is just
// 4 conflict-free ds_read_b32 + ~5 VALU. Each thread handles px tid*4 and
// 1024+tid*4 so every hr load / out store is a fully-contiguous 1 KB wave
// transaction. Non-temporal on the 201 MB single-use hr/out streams (R2 A/B
// showed plain stores cost ~12 us via write-allocate pollution).
#define KO_W 514
__global__ __launch_bounds__(256) void k_out(
    const float* __restrict__ A, const float* __restrict__ Bb,
    const float* __restrict__ hr, float* __restrict__ out,
    int hl, int wl, int Hh, int Wh) {
  __shared__ float Ay[KO_W];
  __shared__ float By[KO_W];

  const int y = blockIdx.x;
  const int bc = blockIdx.y;
  const int tid = threadIdx.x;

  const float scy = (float)(hl - 1) / (float)(Hh - 1);
  const float scx = (float)(wl - 1) / (float)(Wh - 1);

  float fy = (float)y * scy;
  int y0 = (int)fy;
  if (y0 > hl - 1) y0 = hl - 1;
  int y1 = y0 + 1;
  if (y1 > hl - 1) y1 = hl - 1;
  const float wy = fy - (float)y0;

  const size_t lrBase = (size_t)bc * hl * wl;
  const float* __restrict__ A0 = A + lrBase + (size_t)y0 * wl;
  const float* __restrict__ A1 = A + lrBase + (size_t)y1 * wl;
  const float* __restrict__ B0 = Bb + lrBase + (size_t)y0 * wl;
  const float* __restrict__ B1 = Bb + lrBase + (size_t)y1 * wl;

  // Stage: thread i y-lerps LR cols 2i, 2i+1 (512 cols total, b64 loads).
  {
    const int c2 = 2 * tid;
    float2 a0 = *(const float2*)(A0 + c2);
    float2 a1 = *(const float2*)(A1 + c2);
    float2 b0 = *(const float2*)(B0 + c2);
    float2 b1 = *(const float2*)(B1 + c2);
    float ay0 = a0.x + (a1.x - a0.x) * wy;
    float ay1 = a0.y + (a1.y - a0.y) * wy;
    float by0 = b0.x + (b1.x - b0.x) * wy;
    float by1 = b0.y + (b1.y - b0.y) * wy;
    *(float2*)&Ay[c2] = make_float2(ay0, ay1);
    *(float2*)&By[c2] = make_float2(by0, by1);
    if (tid == 255) {  // pad entry 512 (only touched when wx ~= 0 at x=2047)
      Ay[512] = ay1;
      By[512] = by1;
    }
  }

  // hr loads issued before the barrier; latency overlaps staging drain.
  const size_t rowBase = ((size_t)bc * Hh + y) * Wh;
  const int xg0 = tid * 4;          // first f4: fully contiguous 1 KB / wave
  const int xg1 = 1024 + tid * 4;   // second f4
  f4 h0 = __builtin_nontemporal_load((const f4*)(hr + rowBase + xg0));
  f4 h1 = __builtin_nontemporal_load((const f4*)(hr + rowBase + xg1));

  __syncthreads();

  f4 res0, res1;
#pragma unroll
  for (int j = 0; j < 4; ++j) {
    float fx = (float)(xg0 + j) * scx;
    int x0 = (int)fx;
    float wx = fx - (float)x0;
    float a = Ay[x0] + (Ay[x0 + 1] - Ay[x0]) * wx;
    float b = By[x0] + (By[x0 + 1] - By[x0]) * wx;
    res0[j] = a * h0[j] + b;
  }
#pragma unroll
  for (int j = 0; j < 4; ++j) {
    float fx = (float)(xg1 + j) * scx;
    int x0 = (int)fx;
    float wx = fx - (float)x0;
    float a = Ay[x0] + (Ay[x0 + 1] - Ay[x0]) * wx;
    float b = By[x0] + (By[x0 + 1] - By[x0]) * wx;
    res1[j] = a * h1[j] + b;
  }
  __builtin_nontemporal_store(res0, (f4*)(out + rowBase + xg0));
  __builtin_nontemporal_store(res1, (f4*)(out + rowBase + xg1));
}

extern "C" void kernel_launch(void* const* d_in, const int* in_sizes, int n_in,
                              void* d_out, int out_size, void* d_ws, size_t ws_size,
                              hipStream_t stream) {
  const float* lrx = (const float*)d_in[0];
  const float* lry = (const float*)d_in[1];
  const float* hrx = (const float*)d_in[2];
  float* out = (float*)d_out;

  const int BC = 12;  // 4 batch * 3 channels
  const int hl = 512, wl = 512;
  const int Hh = 2048, Wh = 2048;

  float* A = (float*)d_ws;
  float* B = A + (size_t)BC * hl * wl;

  dim3 g1(wl / TILE, hl / TILE, BC);
  dim3 b1(32, 8);
  k_ab<<<g1, b1, 0, stream>>>(lrx, lry, A, B, hl, wl);

  dim3 g2(Hh, BC);  // one block per HR row per plane
  dim3 b2(256);
  k_out<<<g2, b2, 0, stream>>>(A, B, hrx, out, hl, wl, Hh, Wh);
}

// Round 5
// 359.048 us; speedup vs baseline: 1.0287x; 1.0287x over previous
//
#include <hip/hip_runtime.h>

#define RR 8
#define TILE 32
#define EXT (TILE + 2 * RR)   // 48

typedef float f4 __attribute__((ext_vector_type(4)));

// Kernel 1: per low-res pixel A = cov/(var+eps), b = mean_y - A*mean_x via
// clamped 17x17 box sums (zero-pad OOB + analytic N). Separable with
// register sliding windows to minimize LDS instruction count.
// Output: interleaved (A,b) float2 so k_out reads pairs with one b64.
__global__ __launch_bounds__(256) void k_ab(
    const float* __restrict__ lrx, const float* __restrict__ lry,
    float2* __restrict__ ABout, int H, int W) {
  __shared__ float sx[EXT][EXT];
  __shared__ float sy[EXT][EXT];
  __shared__ float hx[EXT][TILE];
  __shared__ float hy[EXT][TILE];
  __shared__ float hxy[EXT][TILE];
  __shared__ float hxx[EXT][TILE];

  const int bc = blockIdx.z;
  const size_t plane = (size_t)bc * H * W;
  const float* __restrict__ px = lrx + plane;
  const float* __restrict__ py = lry + plane;
  const int tx0 = blockIdx.x * TILE;
  const int ty0 = blockIdx.y * TILE;
  const int tid = threadIdx.y * 32 + threadIdx.x;  // block = 32x8 = 256

  // Stage 48x48 region. Interior blocks (no clamping needed): float4 loads.
  const bool interior = (tx0 >= RR) && (ty0 >= RR) &&
                        (tx0 + TILE + RR <= W) && (ty0 + TILE + RR <= H);
  if (interior) {
    const size_t base = (size_t)(ty0 - RR) * W + (tx0 - RR);
    for (int i = tid; i < EXT * (EXT / 4); i += 256) {  // 48*12 = 576
      int r = i / (EXT / 4);
      int c4 = (i - r * (EXT / 4)) * 4;
      size_t o = base + (size_t)r * W + c4;
      *(float4*)&sx[r][c4] = *(const float4*)(px + o);
      *(float4*)&sy[r][c4] = *(const float4*)(py + o);
    }
  } else {
    for (int i = tid; i < EXT * EXT; i += 256) {
      int r = i / EXT, c = i % EXT;
      int gy = ty0 + r - RR, gx = tx0 + c - RR;
      float vx = 0.f, vy = 0.f;
      if (gy >= 0 && gy < H && gx >= 0 && gx < W) {
        size_t o = (size_t)gy * W + gx;
        vx = px[o];
        vy = py[o];
      }
      sx[r][c] = vx;
      sy[r][c] = vy;
    }
  }
  __syncthreads();

  // Horizontal 17-tap sums: 48 rows x 8 groups of 4 outputs = 384 work items.
  for (int q = tid; q < EXT * (TILE / 4); q += 256) {
    int r = q >> 3;
    int c0 = (q & 7) * 4;
    float xv[20], yv[20];
#pragma unroll
    for (int t = 0; t < 5; ++t) {
      float4 x4 = *(const float4*)&sx[r][c0 + 4 * t];
      float4 y4 = *(const float4*)&sy[r][c0 + 4 * t];
      xv[4 * t + 0] = x4.x; xv[4 * t + 1] = x4.y; xv[4 * t + 2] = x4.z; xv[4 * t + 3] = x4.w;
      yv[4 * t + 0] = y4.x; yv[4 * t + 1] = y4.y; yv[4 * t + 2] = y4.z; yv[4 * t + 3] = y4.w;
    }
    float pv[20], qv[20];
#pragma unroll
    for (int i = 0; i < 20; ++i) { pv[i] = xv[i] * yv[i]; qv[i] = xv[i] * xv[i]; }
    float ax = 0.f, ay = 0.f, axy = 0.f, axx = 0.f;
#pragma unroll
    for (int i = 0; i < 17; ++i) { ax += xv[i]; ay += yv[i]; axy += pv[i]; axx += qv[i]; }
    float4 ox, oy, oxy, oxx;
    ox.x = ax; oy.x = ay; oxy.x = axy; oxx.x = axx;
#pragma unroll
    for (int j = 1; j < 4; ++j) {
      ax += xv[j + 16] - xv[j - 1];
      ay += yv[j + 16] - yv[j - 1];
      axy += pv[j + 16] - pv[j - 1];
      axx += qv[j + 16] - qv[j - 1];
      (&ox.x)[j] = ax; (&oy.x)[j] = ay; (&oxy.x)[j] = axy; (&oxx.x)[j] = axx;
    }
    *(float4*)&hx[r][c0] = ox;
    *(float4*)&hy[r][c0] = oy;
    *(float4*)&hxy[r][c0] = oxy;
    *(float4*)&hxx[r][c0] = oxx;
  }
  __syncthreads();

  // Vertical 17-tap: thread (tx, ty) computes rows ty*4..ty*4+3 at col tx.
  const int c = threadIdx.x;
  const int r0 = threadIdx.y * 4;
  float vx[20], vy[20], vxy[20], vxx[20];
#pragma unroll
  for (int i = 0; i < 20; ++i) {
    vx[i] = hx[r0 + i][c];
    vy[i] = hy[r0 + i][c];
    vxy[i] = hxy[r0 + i][c];
    vxx[i] = hxx[r0 + i][c];
  }
  float sX = 0.f, sY = 0.f, sXY = 0.f, sXX = 0.f;
#pragma unroll
  for (int i = 0; i < 17; ++i) { sX += vx[i]; sY += vy[i]; sXY += vxy[i]; sXX += vxx[i]; }

  const int gx = tx0 + c;
  const int nx = min(gx + RR, W - 1) - max(gx - RR, 0) + 1;
#pragma unroll
  for (int j = 0; j < 4; ++j) {
    if (j > 0) {
      sX += vx[j + 16] - vx[j - 1];
      sY += vy[j + 16] - vy[j - 1];
      sXY += vxy[j + 16] - vxy[j - 1];
      sXX += vxx[j + 16] - vxx[j - 1];
    }
    const int gy = ty0 + r0 + j;
    const int ny = min(gy + RR, H - 1) - max(gy - RR, 0) + 1;
    float inv = 1.f / (float)(nx * ny);
    float mx = sX * inv;
    float my = sY * inv;
    float cov = sXY * inv - mx * my;
    float var = sXX * inv - mx * mx;
    float a = cov / (var + 1e-8f);
    float bv = my - a * mx;
    size_t o = plane + (size_t)gy * W + gx;
    ABout[o] = make_float2(a, bv);
  }
}

// Kernel 2: bilinear align-corners upsample of (A,b) fused with out = A*hr+b.
// R1's winning structure: 256 threads x 4 px x 4 HR rows, stage 3 RAW LR
// rows {v..v+2} (scy=511/2047~0.2496 -> 4 HR rows need <=3 LR rows), nt
// load on hr / nt store on out, hr loads issued before the barrier.
// NEW vs R1: LDS traffic cut 5x. (A,b) interleaved float2, and since
// 3*scx < 1 a thread's 4 px span only LR cols l0..l0+2: per HR row read
// just 6 ds_read_b64 (3-wide window from 2 rows), y-lerp the window once,
// then per-px select lo/hi via cndmask + x-lerp. 24 b64/thread vs R1's
// 128 b32 -> LDS pipe drops from ~60us (tied with HBM) to ~12us.
#define ROWS 4
#define KO_LDSW 264
__global__ __launch_bounds__(256) void k_out(
    const float2* __restrict__ AB, const float* __restrict__ hr,
    float* __restrict__ out, int hl, int wl, int Hh, int Wh) {
  __shared__ float2 ABs[3][KO_LDSW];

  const int yb = blockIdx.y * ROWS;  // first of 4 HR rows
  const int bc = blockIdx.z;
  const int xb = blockIdx.x * 1024;  // first HR pixel of this block
  const int tid = threadIdx.x;

  const float scy = (float)(hl - 1) / (float)(Hh - 1);
  const float scx = (float)(wl - 1) / (float)(Wh - 1);

  // Base LR row for this 4-row group; rows yb..yb+3 use LR rows v..v+2.
  int v = (int)((float)yb * scy);
  if (v > hl - 1) v = hl - 1;

  // Per-row y-interp params (uniform across the block).
  int ry0[ROWS], ry1[ROWS];
  float wyv[ROWS];
#pragma unroll
  for (int r = 0; r < ROWS; ++r) {
    float fy = (float)(yb + r) * scy;
    int y0 = (int)fy;
    if (y0 > hl - 1) y0 = hl - 1;
    int y1 = y0 + 1;
    if (y1 > hl - 1) y1 = hl - 1;
    wyv[r] = fy - (float)y0;
    ry0[r] = y0 - v;  // in {0,1}
    ry1[r] = y1 - v;  // in {0,1,2}
  }

  const int x0base = (int)((float)xb * scx);
  const size_t lrBase = (size_t)bc * hl * wl;

  // Stage raw LR rows v..v+2 (row/col clamped), 264 interleaved pairs each.
  for (int i = tid; i < 3 * KO_LDSW; i += 256) {
    int rr = i / KO_LDSW;  // 0..2 (magic-mul)
    int cc = i - rr * KO_LDSW;
    int xl = x0base + cc;
    if (xl > wl - 1) xl = wl - 1;
    int yr = v + rr;
    if (yr > hl - 1) yr = hl - 1;
    ABs[rr][cc] = AB[lrBase + (size_t)yr * wl + xl];
  }

  // Per-pixel x params, shared across the 4 rows. Since 3*scx < 1, the 4 px
  // of this thread span x0 values {l0, l0+1} only: d[j] = x0_j - x0_0.
  const int xg = xb + tid * 4;
  float wxv[4];
  int dsel[4];
  int l0;
  {
    float fx0 = (float)xg * scx;
    int x00 = (int)fx0;
    l0 = x00 - x0base;
    wxv[0] = fx0 - (float)x00;
    dsel[0] = 0;
#pragma unroll
    for (int j = 1; j < 4; ++j) {
      float fx = (float)(xg + j) * scx;
      int x0 = (int)fx;
      wxv[j] = fx - (float)x0;
      dsel[j] = x0 - x00;  // 0 or 1
    }
  }

  // Issue all 4 hr loads before the barrier (latency overlaps staging).
  const size_t hrBase = ((size_t)bc * Hh + yb) * Wh + xg;
  f4 h[ROWS];
#pragma unroll
  for (int r = 0; r < ROWS; ++r)
    h[r] = __builtin_nontemporal_load((const f4*)(hr + hrBase + (size_t)r * Wh));

  __syncthreads();

#pragma unroll
  for (int r = 0; r < ROWS; ++r) {
    const float2* __restrict__ R0 = ABs[ry0[r]];
    const float2* __restrict__ R1 = ABs[ry1[r]];
    const float wy = wyv[r];
    // 3-wide (A,b) window from both rows; y-lerp once.
    float2 q00 = R0[l0], q01 = R0[l0 + 1], q02 = R0[l0 + 2];
    float2 q10 = R1[l0], q11 = R1[l0 + 1], q12 = R1[l0 + 2];
    float w0a = q00.x + (q10.x - q00.x) * wy;
    float w0b = q00.y + (q10.y - q00.y) * wy;
    float w1a = q01.x + (q11.x - q01.x) * wy;
    float w1b = q01.y + (q11.y - q01.y) * wy;
    float w2a = q02.x + (q12.x - q02.x) * wy;
    float w2b = q02.y + (q12.y - q02.y) * wy;
    f4 res;
#pragma unroll
    for (int j = 0; j < 4; ++j) {
      float loa = dsel[j] ? w1a : w0a;
      float lob = dsel[j] ? w1b : w0b;
      float hia = dsel[j] ? w2a : w1a;
      float hib = dsel[j] ? w2b : w1b;
      float w = wxv[j];
      float a = loa + (hia - loa) * w;
      float b = lob + (hib - lob) * w;
      res[j] = a * h[r][j] + b;
    }
    __builtin_nontemporal_store(res, (f4*)(out + hrBase + (size_t)r * Wh));
  }
}

extern "C" void kernel_launch(void* const* d_in, const int* in_sizes, int n_in,
                              void* d_out, int out_size, void* d_ws, size_t ws_size,
                              hipStream_t stream) {
  const float* lrx = (const float*)d_in[0];
  const float* lry = (const float*)d_in[1];
  const float* hrx = (const float*)d_in[2];
  float* out = (float*)d_out;

  const int BC = 12;  // 4 batch * 3 channels
  const int hl = 512, wl = 512;
  const int Hh = 2048, Wh = 2048;

  float2* AB = (float2*)d_ws;  // interleaved (A,b), 25 MB

  dim3 g1(wl / TILE, hl / TILE, BC);
  dim3 b1(32, 8);
  k_ab<<<g1, b1, 0, stream>>>(lrx, lry, AB, hl, wl);

  dim3 g2(Wh / 1024, Hh / ROWS, BC);
  dim3 b2(256);
  k_out<<<g2, b2, 0, stream>>>(AB, hrx, out, hl, wl, Hh, Wh);
}

// Round 6
// 356.425 us; speedup vs baseline: 1.0363x; 1.0074x over previous
//
#include <hip/hip_runtime.h>

#define RR 8
#define TILE 32
#define EXT (TILE + 2 * RR)   // 48

typedef float f4 __attribute__((ext_vector_type(4)));

// Kernel 1: per low-res pixel A = cov/(var+eps), b = mean_y - A*mean_x via
// clamped 17x17 box sums (zero-pad OOB + analytic N). Separable with
// register sliding windows to minimize LDS instruction count.
// Output: interleaved (A,b) float2 so k_out reads pairs with one b64.
__global__ __launch_bounds__(256) void k_ab(
    const float* __restrict__ lrx, const float* __restrict__ lry,
    float2* __restrict__ ABout, int H, int W) {
  __shared__ float sx[EXT][EXT];
  __shared__ float sy[EXT][EXT];
  __shared__ float hx[EXT][TILE];
  __shared__ float hy[EXT][TILE];
  __shared__ float hxy[EXT][TILE];
  __shared__ float hxx[EXT][TILE];

  const int bc = blockIdx.z;
  const size_t plane = (size_t)bc * H * W;
  const float* __restrict__ px = lrx + plane;
  const float* __restrict__ py = lry + plane;
  const int tx0 = blockIdx.x * TILE;
  const int ty0 = blockIdx.y * TILE;
  const int tid = threadIdx.y * 32 + threadIdx.x;  // block = 32x8 = 256

  // Stage 48x48 region. Interior blocks (no clamping needed): float4 loads.
  const bool interior = (tx0 >= RR) && (ty0 >= RR) &&
                        (tx0 + TILE + RR <= W) && (ty0 + TILE + RR <= H);
  if (interior) {
    const size_t base = (size_t)(ty0 - RR) * W + (tx0 - RR);
    for (int i = tid; i < EXT * (EXT / 4); i += 256) {  // 48*12 = 576
      int r = i / (EXT / 4);
      int c4 = (i - r * (EXT / 4)) * 4;
      size_t o = base + (size_t)r * W + c4;
      *(float4*)&sx[r][c4] = *(const float4*)(px + o);
      *(float4*)&sy[r][c4] = *(const float4*)(py + o);
    }
  } else {
    for (int i = tid; i < EXT * EXT; i += 256) {
      int r = i / EXT, c = i % EXT;
      int gy = ty0 + r - RR, gx = tx0 + c - RR;
      float vx = 0.f, vy = 0.f;
      if (gy >= 0 && gy < H && gx >= 0 && gx < W) {
        size_t o = (size_t)gy * W + gx;
        vx = px[o];
        vy = py[o];
      }
      sx[r][c] = vx;
      sy[r][c] = vy;
    }
  }
  __syncthreads();

  // Horizontal 17-tap sums: 48 rows x 8 groups of 4 outputs = 384 work items.
  for (int q = tid; q < EXT * (TILE / 4); q += 256) {
    int r = q >> 3;
    int c0 = (q & 7) * 4;
    float xv[20], yv[20];
#pragma unroll
    for (int t = 0; t < 5; ++t) {
      float4 x4 = *(const float4*)&sx[r][c0 + 4 * t];
      float4 y4 = *(const float4*)&sy[r][c0 + 4 * t];
      xv[4 * t + 0] = x4.x; xv[4 * t + 1] = x4.y; xv[4 * t + 2] = x4.z; xv[4 * t + 3] = x4.w;
      yv[4 * t + 0] = y4.x; yv[4 * t + 1] = y4.y; yv[4 * t + 2] = y4.z; yv[4 * t + 3] = y4.w;
    }
    float pv[20], qv[20];
#pragma unroll
    for (int i = 0; i < 20; ++i) { pv[i] = xv[i] * yv[i]; qv[i] = xv[i] * xv[i]; }
    float ax = 0.f, ay = 0.f, axy = 0.f, axx = 0.f;
#pragma unroll
    for (int i = 0; i < 17; ++i) { ax += xv[i]; ay += yv[i]; axy += pv[i]; axx += qv[i]; }
    float4 ox, oy, oxy, oxx;
    ox.x = ax; oy.x = ay; oxy.x = axy; oxx.x = axx;
#pragma unroll
    for (int j = 1; j < 4; ++j) {
      ax += xv[j + 16] - xv[j - 1];
      ay += yv[j + 16] - yv[j - 1];
      axy += pv[j + 16] - pv[j - 1];
      axx += qv[j + 16] - qv[j - 1];
      (&ox.x)[j] = ax; (&oy.x)[j] = ay; (&oxy.x)[j] = axy; (&oxx.x)[j] = axx;
    }
    *(float4*)&hx[r][c0] = ox;
    *(float4*)&hy[r][c0] = oy;
    *(float4*)&hxy[r][c0] = oxy;
    *(float4*)&hxx[r][c0] = oxx;
  }
  __syncthreads();

  // Vertical 17-tap: thread (tx, ty) computes rows ty*4..ty*4+3 at col tx.
  const int c = threadIdx.x;
  const int r0 = threadIdx.y * 4;
  float vx[20], vy[20], vxy[20], vxx[20];
#pragma unroll
  for (int i = 0; i < 20; ++i) {
    vx[i] = hx[r0 + i][c];
    vy[i] = hy[r0 + i][c];
    vxy[i] = hxy[r0 + i][c];
    vxx[i] = hxx[r0 + i][c];
  }
  float sX = 0.f, sY = 0.f, sXY = 0.f, sXX = 0.f;
#pragma unroll
  for (int i = 0; i < 17; ++i) { sX += vx[i]; sY += vy[i]; sXY += vxy[i]; sXX += vxx[i]; }

  const int gx = tx0 + c;
  const int nx = min(gx + RR, W - 1) - max(gx - RR, 0) + 1;
#pragma unroll
  for (int j = 0; j < 4; ++j) {
    if (j > 0) {
      sX += vx[j + 16] - vx[j - 1];
      sY += vy[j + 16] - vy[j - 1];
      sXY += vxy[j + 16] - vxy[j - 1];
      sXX += vxx[j + 16] - vxx[j - 1];
    }
    const int gy = ty0 + r0 + j;
    const int ny = min(gy + RR, H - 1) - max(gy - RR, 0) + 1;
    float inv = 1.f / (float)(nx * ny);
    float mx = sX * inv;
    float my = sY * inv;
    float cov = sXY * inv - mx * my;
    float var = sXX * inv - mx * mx;
    float a = cov / (var + 1e-8f);
    float bv = my - a * mx;
    size_t o = plane + (size_t)gy * W + gx;
    ABout[o] = make_float2(a, bv);
  }
}

// Kernel 2: bilinear align-corners upsample of (A,b) fused with out = A*hr+b.
// BARRIER-FREE: no LDS, no __syncthreads. Since 3*scx < 1 and 3*scy < 1,
// each thread's 4px x 4row patch needs only a 3x3 window of (A,b) pairs:
// 9 global b64 loads straight from the 25 MB L2/L3-resident AB array into
// registers (lane windows advance ~1 pair/lane -> quasi-contiguous,
// broadcast-friendly). Rows select from the register window via
// constant-indexed ternary chains (cndmask, no scratch). Kernel is a pure
// stream: 9 L2 loads + 4 nt hr loads + VALU + 4 nt stores. nt kept on
// hr/out (R2 A/B: plain stores cost ~12 us via write-allocate pollution).
#define ROWS 4
__global__ __launch_bounds__(256) void k_out(
    const float2* __restrict__ AB, const float* __restrict__ hr,
    float* __restrict__ out, int hl, int wl, int Hh, int Wh) {
  const int yb = blockIdx.y * ROWS;  // first of 4 HR rows
  const int bc = blockIdx.z;
  const int xb = blockIdx.x * 1024;  // first HR pixel of this block
  const int tid = threadIdx.x;

  const float scy = (float)(hl - 1) / (float)(Hh - 1);
  const float scx = (float)(wl - 1) / (float)(Wh - 1);

  // Base LR row for this 4-row group; rows yb..yb+3 use LR rows v..v+2.
  int v = (int)((float)yb * scy);
  if (v > hl - 1) v = hl - 1;

  // Per-pixel x params. 3*scx < 1 -> the 4 px span x0 in {x00, x00+1} only.
  const int xg = xb + tid * 4;
  float wxv[4];
  int dsel[4];
  int x00;
  {
    float fx0 = (float)xg * scx;
    x00 = (int)fx0;
    wxv[0] = fx0 - (float)x00;
    dsel[0] = 0;
#pragma unroll
    for (int j = 1; j < 4; ++j) {
      float fx = (float)(xg + j) * scx;
      int x0 = (int)fx;
      wxv[j] = fx - (float)x0;
      dsel[j] = x0 - x00;  // 0 or 1
    }
  }

  // Load the 3x3 (A,b) window into registers (col/row clamped).
  const size_t lrBase = (size_t)bc * hl * wl;
  const int xc0 = x00;  // x00 <= 510 always (2047*scx < 511)
  const int xc1 = (x00 + 1 > wl - 1) ? wl - 1 : x00 + 1;
  const int xc2 = (x00 + 2 > wl - 1) ? wl - 1 : x00 + 2;
  float2 q[3][3];
#pragma unroll
  for (int rr = 0; rr < 3; ++rr) {
    int yr = v + rr;
    if (yr > hl - 1) yr = hl - 1;
    const float2* __restrict__ Rp = AB + lrBase + (size_t)yr * wl;
    q[rr][0] = Rp[xc0];
    q[rr][1] = Rp[xc1];
    q[rr][2] = Rp[xc2];
  }

  // hr loads (independent of AB loads; all 13 loads in flight together).
  const size_t hrBase = ((size_t)bc * Hh + yb) * Wh + xg;
  f4 h[ROWS];
#pragma unroll
  for (int r = 0; r < ROWS; ++r)
    h[r] = __builtin_nontemporal_load((const f4*)(hr + hrBase + (size_t)r * Wh));

#pragma unroll
  for (int r = 0; r < ROWS; ++r) {
    float fy = (float)(yb + r) * scy;
    int y0 = (int)fy;
    if (y0 > hl - 1) y0 = hl - 1;
    int y1 = y0 + 1;
    if (y1 > hl - 1) y1 = hl - 1;
    const float wy = fy - (float)y0;
    const int i0 = y0 - v;  // 0 or 1
    const int i1 = y1 - v;  // 0, 1, or 2
    // Row-select from the register window (constant indices, cndmask).
    float2 p00 = i0 ? q[1][0] : q[0][0];
    float2 p01 = i0 ? q[1][1] : q[0][1];
    float2 p02 = i0 ? q[1][2] : q[0][2];
    float2 p10 = (i1 == 0) ? q[0][0] : ((i1 == 1) ? q[1][0] : q[2][0]);
    float2 p11 = (i1 == 0) ? q[0][1] : ((i1 == 1) ? q[1][1] : q[2][1]);
    float2 p12 = (i1 == 0) ? q[0][2] : ((i1 == 1) ? q[1][2] : q[2][2]);
    // y-lerp the 3-wide window once.
    float w0a = p00.x + (p10.x - p00.x) * wy;
    float w0b = p00.y + (p10.y - p00.y) * wy;
    float w1a = p01.x + (p11.x - p01.x) * wy;
    float w1b = p01.y + (p11.y - p01.y) * wy;
    float w2a = p02.x + (p12.x - p02.x) * wy;
    float w2b = p02.y + (p12.y - p02.y) * wy;
    f4 res;
#pragma unroll
    for (int j = 0; j < 4; ++j) {
      float loa = dsel[j] ? w1a : w0a;
      float lob = dsel[j] ? w1b : w0b;
      float hia = dsel[j] ? w2a : w1a;
      float hib = dsel[j] ? w2b : w1b;
      float w = wxv[j];
      float a = loa + (hia - loa) * w;
      float b = lob + (hib - lob) * w;
      res[j] = a * h[r][j] + b;
    }
    __builtin_nontemporal_store(res, (f4*)(out + hrBase + (size_t)r * Wh));
  }
}

extern "C" void kernel_launch(void* const* d_in, const int* in_sizes, int n_in,
                              void* d_out, int out_size, void* d_ws, size_t ws_size,
                              hipStream_t stream) {
  const float* lrx = (const float*)d_in[0];
  const float* lry = (const float*)d_in[1];
  const float* hrx = (const float*)d_in[2];
  float* out = (float*)d_out;

  const int BC = 12;  // 4 batch * 3 channels
  const int hl = 512, wl = 512;
  const int Hh = 2048, Wh = 2048;

  float2* AB = (float2*)d_ws;  // interleaved (A,b), 25 MB

  dim3 g1(wl / TILE, hl / TILE, BC);
  dim3 b1(32, 8);
  k_ab<<<g1, b1, 0, stream>>>(lrx, lry, AB, hl, wl);

  dim3 g2(Wh / 1024, Hh / ROWS, BC);
  dim3 b2(256);
  k_out<<<g2, b2, 0, stream>>>(AB, hrx, out, hl, wl, Hh, Wh);
}